// Round 1
// baseline (436.636 us; speedup 1.0000x reference)
//
#include <hip/hip_runtime.h>
#include <math.h>

// ProtoLoss: loss = mean_n( -2*sim[n,fam[n]] + logsumexp_f(4*sim[n,f]) )
// sim = (E . P_f) / max(||e||*||p_f||, 1e-8), P = segment-mean of E by family.
// N=262144, D=128, F=64, T=0.5 -> sim/T^2 = 4*sim, -pos/T = -2*pos.

#define D_DIM 128
#define F_NUM 64
#define PA 16                         // partial copies for pass A (low atomic contention)
#define SUM_ELEMS (F_NUM * D_DIM)     // 8192

// ---------------- Pass A: per-family sums + counts --------------------------
// Each block: LDS accumulator [64][128] via LDS atomics; 8 rows in flight
// (32 lanes x float4 per row, coalesced); flush with global fp32 atomics into
// one of PA partial copies (32 writers/address -> negligible serialization).
__global__ __launch_bounds__(256) void pass_a_sums(
    const float* __restrict__ emb, const int* __restrict__ fam,
    float* __restrict__ psum, int* __restrict__ pcnt,
    int N, int rowsPerBlock)
{
  __shared__ float lsum[SUM_ELEMS];
  __shared__ int   lcnt[F_NUM];
  int t = threadIdx.x;
  for (int i = t; i < SUM_ELEMS; i += 256) lsum[i] = 0.f;
  if (t < F_NUM) lcnt[t] = 0;
  __syncthreads();

  int subrow = t >> 5, l32 = t & 31;
  int base = blockIdx.x * rowsPerBlock;
  int rend = base + rowsPerBlock; if (rend > N) rend = N;
  const float4* emb4 = (const float4*)emb;
  for (int r = base + subrow; r < rend; r += 8) {
    int f = fam[r];
    float4 v = emb4[r * 32 + l32];
    float* dst = &lsum[f * D_DIM + (l32 << 2)];
    atomicAdd(dst + 0, v.x);            // ds_add_f32, ~4-way bank alias max
    atomicAdd(dst + 1, v.y);
    atomicAdd(dst + 2, v.z);
    atomicAdd(dst + 3, v.w);
    if (l32 == 0) atomicAdd(&lcnt[f], 1);
  }
  __syncthreads();

  float* ps = psum + (size_t)(blockIdx.x & (PA - 1)) * SUM_ELEMS;
  for (int i = t; i < SUM_ELEMS; i += 256) unsafeAtomicAdd(&ps[i], lsum[i]);
  int* pc = pcnt + (blockIdx.x & (PA - 1)) * F_NUM;
  if (t < F_NUM) atomicAdd(&pc[t], lcnt[t]);
}

// ---------------- Pass B: protos + 1/||p||, swizzled layout -----------------
// protoW layout: [wave w][chunk c][fi][j] = proto[f=16w+fi][d=4c+j] so that a
// wave in pass C reads 16 contiguous float4 per chunk with a wave-uniform
// address -> s_load (scalar pipe), zero VALU/LDS cost.
__global__ __launch_bounds__(256) void pass_b_protos(
    const float* __restrict__ psum, const int* __restrict__ pcnt,
    float* __restrict__ protoW, float* __restrict__ pinv)
{
  __shared__ float sp[F_NUM][D_DIM];     // 32 KB
  __shared__ float scnt[F_NUM];
  int t = threadIdx.x;
  if (t < F_NUM) {
    int c = 0;
    for (int p = 0; p < PA; ++p) c += pcnt[p * F_NUM + t];
    scnt[t] = fmaxf((float)c, 1.0f);
  }
  __syncthreads();
  for (int idx = t; idx < SUM_ELEMS; idx += 256) {
    float s = 0.f;
    for (int p = 0; p < PA; ++p) s += psum[p * SUM_ELEMS + idx];
    int f = idx >> 7;
    sp[f][idx & 127] = s / scnt[f];
  }
  __syncthreads();
  if (t < F_NUM) {
    float n2 = 0.f;
    for (int d = 0; d < D_DIM; ++d) n2 = fmaf(sp[t][d], sp[t][d], n2);
    // zero-count family => proto=0 => dot=0; finite pinv keeps sim = 0.
    pinv[t] = 1.0f / sqrtf(fmaxf(n2, 1e-24f));
  }
  __syncthreads();
  for (int idx = t; idx < SUM_ELEMS; idx += 256) {
    int j = idx & 3, fi = (idx >> 2) & 15, c = (idx >> 6) & 31, w = idx >> 11;
    protoW[idx] = sp[w * 16 + fi][c * 4 + j];
  }
}

// ---------------- Pass C: sims + per-row loss, per-block sum ----------------
// Block tile = 64 rows. Wave w owns families [16w,16w+16); lane = row.
// e-tile in LDS, stride 129 -> conflict-free b32 reads. Protos via s_load.
// LSE uses fixed max 4 (sim<=1): lse = 4 + ln(sum exp(4s-4)); exact, no pass.
__global__ __launch_bounds__(256) void pass_c_loss(
    const float* __restrict__ emb, const int* __restrict__ fam,
    const float* __restrict__ protoW, const float* __restrict__ pinv,
    float* __restrict__ block_sums, int N)
{
  __shared__ float se[64 * 129];       // e rows, padded
  __shared__ float sdots[64 * 65];     // sims, padded
  __shared__ float spart[4 * 64];      // per-quarter exp partial sums
  int t = threadIdx.x;
  int row0 = blockIdx.x * 64;

  // stage 64 rows (coalesced float4 global -> scalar LDS writes)
  const float4* src = (const float4*)emb;
  #pragma unroll
  for (int i = 0; i < 8; ++i) {
    int idx = (i * 256 + t) * 4;       // 0..8188
    int r = idx >> 7, d = idx & 127;
    int gr = row0 + r;
    float4 v = make_float4(0.f, 0.f, 0.f, 0.f);
    if (gr < N) v = src[gr * 32 + (d >> 2)];
    float* dst = &se[r * 129 + d];
    dst[0] = v.x; dst[1] = v.y; dst[2] = v.z; dst[3] = v.w;
  }
  __syncthreads();

  int wave = t >> 6, lane = t & 63;
  int wu = __builtin_amdgcn_readfirstlane(wave);     // force SGPR -> s_load
  const float4* pw = (const float4*)(protoW + (wu << 11));   // w*2048 floats
  const float* erow = &se[lane * 129];

  float dots[16];
  #pragma unroll
  for (int i = 0; i < 16; ++i) dots[i] = 0.f;
  float n2 = 0.f;

  #pragma unroll 1
  for (int c = 0; c < 32; ++c) {
    float ex = erow[c * 4 + 0], ey = erow[c * 4 + 1];
    float ez = erow[c * 4 + 2], ew = erow[c * 4 + 3];
    n2 = fmaf(ex, ex, fmaf(ey, ey, fmaf(ez, ez, fmaf(ew, ew, n2))));
    #pragma unroll
    for (int fi = 0; fi < 16; ++fi) {
      float4 p = pw[c * 16 + fi];      // wave-uniform -> s_load_dwordx4
      dots[fi] = fmaf(ex, p.x, fmaf(ey, p.y, fmaf(ez, p.z, fmaf(ew, p.w, dots[fi]))));
    }
  }

  float inv_en = 1.0f / sqrtf(n2);     // padded rows: inf, result unused
  #pragma unroll
  for (int fi = 0; fi < 16; ++fi) {
    int f = (wu << 4) + fi;
    float sim = dots[fi] * inv_en * pinv[f];
    sdots[lane * 65 + f] = sim;        // bank = (lane+f)%32, conflict-free
  }
  __syncthreads();

  {
    int row = t & 63, q = t >> 6;
    float s = 0.f;
    #pragma unroll
    for (int fi = 0; fi < 16; ++fi) {
      float sim = sdots[row * 65 + q * 16 + fi];
      s += __expf(4.0f * sim - 4.0f);  // arg in [-8,0]: no overflow/underflow
    }
    spart[q * 64 + row] = s;
  }
  __syncthreads();

  float per = 0.f;
  if (t < 64) {
    int gr = row0 + t;
    if (gr < N) {
      float s = spart[t] + spart[64 + t] + spart[128 + t] + spart[192 + t];
      int fr = fam[gr];
      float pos = sdots[t * 65 + fr];
      per = 4.0f + __logf(s) - 2.0f * pos;
    }
  }
  for (int off = 32; off; off >>= 1) per += __shfl_down(per, off);
  if (t == 0) block_sums[blockIdx.x] = per;
}

// ---------------- Pass D: final reduction -----------------------------------
__global__ __launch_bounds__(256) void pass_d_reduce(
    const float* __restrict__ bs, float* __restrict__ out, int nb, float invN)
{
  __shared__ float red[256];
  int t = threadIdx.x;
  float s = 0.f;
  for (int i = t; i < nb; i += 256) s += bs[i];
  red[t] = s;
  __syncthreads();
  for (int o = 128; o; o >>= 1) {
    if (t < o) red[t] += red[t + o];
    __syncthreads();
  }
  if (t == 0) out[0] = red[0] * invN;
}

extern "C" void kernel_launch(void* const* d_in, const int* in_sizes, int n_in,
                              void* d_out, int out_size, void* d_ws, size_t ws_size,
                              hipStream_t stream) {
  const float* emb = (const float*)d_in[0];
  const int* fam = (const int*)d_in[1];
  int N = in_sizes[0] / D_DIM;         // 262144

  // ws layout (floats): psum[PA*8192] | pcnt[PA*64] | protoW[8192] | pinv[64] | bsums[tiles]
  float* ws = (float*)d_ws;
  float* psum   = ws;
  int*   pcnt   = (int*)(ws + (size_t)PA * SUM_ELEMS);
  float* protoW = ws + (size_t)PA * SUM_ELEMS + PA * F_NUM;
  float* pinv   = protoW + SUM_ELEMS;
  float* bsums  = pinv + F_NUM;
  int numTiles = (N + 63) / 64;        // 4096

  hipMemsetAsync(d_ws, 0, (size_t)(PA * SUM_ELEMS + PA * F_NUM) * 4, stream);

  int gridA = 512;
  int rowsPerBlock = (N + gridA - 1) / gridA;
  pass_a_sums<<<gridA, 256, 0, stream>>>(emb, fam, psum, pcnt, N, rowsPerBlock);
  pass_b_protos<<<1, 256, 0, stream>>>(psum, pcnt, protoW, pinv);
  pass_c_loss<<<numTiles, 256, 0, stream>>>(emb, fam, protoW, pinv, bsums, N);
  pass_d_reduce<<<1, 256, 0, stream>>>(bsums, (float*)d_out, numTiles, 1.0f / (float)N);
}

// Round 2
// 360.196 us; speedup vs baseline: 1.2122x; 1.2122x over previous
//
#include <hip/hip_runtime.h>
#include <math.h>

// ProtoLoss: loss = mean_n( -2*sim[n,fam[n]] + logsumexp_f(4*sim[n,f]) )
// sim = (E.P_f)/(||e||*||p_f||), P = segment-mean of E by family.
// N=262144, D=128, F=64.
// Pipeline: A) segment sums + counts + exact fp32 row norms (private partials,
// NO global atomics)  B) reduce partials -> protos(bf16) + 1/||p||
// C) bf16 MFMA GEMM tile (128 rows x 64 fams, K=128) + fused lse epilogue
// D) final sum.

#define D_DIM 128
#define F_NUM 64

typedef __attribute__((ext_vector_type(8))) short short8;
typedef __attribute__((ext_vector_type(4))) float f32x4;

static __device__ __forceinline__ unsigned short f2bf(float x) {
  union { float f; unsigned u; } v; v.f = x;
  unsigned r = v.u + 0x7FFFu + ((v.u >> 16) & 1u);   // RNE
  return (unsigned short)(r >> 16);
}

// ---------------- Pass A -----------------------------------------------------
// 256 blocks x 1024 thr (16 waves/CU). 32-lane group reads one row/iter as
// float4 (prefetched 1 ahead), LDS-atomic accumulate, exact row-norm via
// cross-lane reduce. Flush = plain coalesced stores to PRIVATE slot.
__global__ __launch_bounds__(1024) void pass_a(
    const float* __restrict__ emb, const int* __restrict__ fam,
    float* __restrict__ psum, int* __restrict__ pcnt,
    float* __restrict__ inv_en, int N)
{
  __shared__ float lsum[F_NUM * D_DIM];   // 32 KB
  __shared__ int   lcnt[F_NUM];
  int t = threadIdx.x;
  for (int i = t; i < F_NUM * D_DIM; i += 1024) lsum[i] = 0.f;
  if (t < F_NUM) lcnt[t] = 0;
  __syncthreads();

  int g = t >> 5, l = t & 31;
  int base = blockIdx.x * 1024;           // rows per block (N/256 = 1024)
  const float4* e4 = (const float4*)emb;

  int r = base + g;
  int    fnext = fam[r];
  float4 vnext = e4[(size_t)r * 32 + l];
  #pragma unroll 1
  for (int i = 0; i < 32; ++i) {
    int f = fnext; float4 v = vnext;
    int rn = r + 32;
    if (i < 31) { fnext = fam[rn]; vnext = e4[(size_t)rn * 32 + l]; }
    float* dst = &lsum[f * D_DIM + (l << 2)];
    atomicAdd(dst + 0, v.x);
    atomicAdd(dst + 1, v.y);
    atomicAdd(dst + 2, v.z);
    atomicAdd(dst + 3, v.w);
    float nq = v.x * v.x + v.y * v.y + v.z * v.z + v.w * v.w;
    nq += __shfl_xor(nq, 1);  nq += __shfl_xor(nq, 2);  nq += __shfl_xor(nq, 4);
    nq += __shfl_xor(nq, 8);  nq += __shfl_xor(nq, 16);
    if (l == 0) { atomicAdd(&lcnt[f], 1); inv_en[r] = rsqrtf(nq); }
    r = rn;
  }
  __syncthreads();

  // private flush: streaming dwordx4 stores (no atomics -> no HBM RMW storm)
  float4* ps4 = (float4*)(psum + (size_t)blockIdx.x * (F_NUM * D_DIM));
  const float4* ls4 = (const float4*)lsum;
  ps4[t] = ls4[t];
  ps4[t + 1024] = ls4[t + 1024];
  if (t < F_NUM) pcnt[blockIdx.x * F_NUM + t] = lcnt[t];
}

// ---------------- Pass B -----------------------------------------------------
// 64 blocks (one per family) x 256 thr: reduce 256 partials, counts, norm.
__global__ __launch_bounds__(256) void pass_b(
    const float* __restrict__ psum, const int* __restrict__ pcnt,
    unsigned short* __restrict__ protoB, float* __restrict__ pinv)
{
  __shared__ float red[256];
  __shared__ float scnt;
  int f = blockIdx.x, t = threadIdx.x;
  int d = t & 127, h = t >> 7;

  // counts
  red[t] = (float)pcnt[t * F_NUM + f];
  __syncthreads();
  for (int o = 128; o; o >>= 1) { if (t < o) red[t] += red[t + o]; __syncthreads(); }
  if (t == 0) scnt = fmaxf(red[0], 1.0f);
  __syncthreads();

  // sums: thread handles (d, half) -> 128 partials each
  float s = 0.f;
  #pragma unroll 4
  for (int i = 0; i < 128; ++i)
    s += psum[(size_t)(h + 2 * i) * (F_NUM * D_DIM) + f * D_DIM + d];
  red[t] = s;
  __syncthreads();
  float proto = 0.f;
  if (t < 128) proto = (red[t] + red[t + 128]) / scnt;
  __syncthreads();

  // norm
  red[t] = (t < 128) ? proto * proto : 0.f;
  __syncthreads();
  for (int o = 128; o; o >>= 1) { if (t < o) red[t] += red[t + o]; __syncthreads(); }
  if (t == 0) pinv[f] = rsqrtf(fmaxf(red[0], 1e-24f));

  if (t < 128) protoB[f * D_DIM + t] = f2bf(proto);
}

// ---------------- Pass C -----------------------------------------------------
// 2048 blocks x 256 thr. Tile: 128 rows x 64 fams, K=128, bf16 MFMA 16x16x32.
// Wave w: rows [w*32, w*32+32) x all 64 fams = 2x4 tiles, 32 MFMAs.
// LDS: A 128x136 bf16 (pad 8 -> conflict-free b128), B 64x136 bf16.
// Epilogue: per-row lse over 64 fams fused in-register (quad shfl_xor).
__global__ __launch_bounds__(256) void pass_c(
    const float* __restrict__ emb, const int* __restrict__ fam,
    const unsigned short* __restrict__ protoB, const float* __restrict__ pinv,
    const float* __restrict__ inv_en, float* __restrict__ bsums)
{
  __shared__ __align__(16) unsigned short sA[128 * 136];   // 34816 B
  __shared__ __align__(16) unsigned short sB[F_NUM * 136]; // 17408 B
  __shared__ float sInvE[128];
  __shared__ int   sFam[128];
  __shared__ float sWp[4];

  int t = threadIdx.x;
  int R0 = blockIdx.x * 128;
  const float4* src = (const float4*)emb;

  // stage A: fp32 -> bf16 (RNE) -> LDS
  #pragma unroll
  for (int it = 0; it < 16; ++it) {
    int idx = it * 256 + t;                 // 0..4095 float4s
    int row = idx >> 5, c4 = idx & 31;
    float4 v = src[(size_t)(R0 + row) * 32 + c4];
    ushort4 u;
    u.x = f2bf(v.x); u.y = f2bf(v.y); u.z = f2bf(v.z); u.w = f2bf(v.w);
    *(ushort4*)&sA[row * 136 + (c4 << 2)] = u;
  }
  // stage B: protos bf16 -> LDS
  const ushort4* pb = (const ushort4*)protoB;
  #pragma unroll
  for (int it = 0; it < 8; ++it) {
    int idx = it * 256 + t;                 // 0..2047 ushort4s
    int f = idx >> 5, c4 = idx & 31;
    *(ushort4*)&sB[f * 136 + (c4 << 2)] = pb[idx];
  }
  if (t < 128) { sInvE[t] = inv_en[R0 + t]; sFam[t] = fam[R0 + t]; }
  __syncthreads();

  int w = t >> 6, lane = t & 63, m16 = lane & 15, q = lane >> 4;
  float pv[4];
  #pragma unroll
  for (int ft = 0; ft < 4; ++ft) pv[ft] = pinv[ft * 16 + m16];

  f32x4 acc[2][4] = {};
  const unsigned short* aB0 = &sA[(w * 32 + m16) * 136 + q * 8];
  const unsigned short* aB1 = aB0 + 16 * 136;
  const unsigned short* bB  = &sB[m16 * 136 + q * 8];

  #pragma unroll
  for (int ks = 0; ks < 4; ++ks) {
    int ko = ks * 32;
    short8 a0 = *(const short8*)(aB0 + ko);
    short8 a1 = *(const short8*)(aB1 + ko);
    short8 b0 = *(const short8*)(bB + ko);
    short8 b1 = *(const short8*)(bB + 16 * 136 + ko);
    short8 b2 = *(const short8*)(bB + 32 * 136 + ko);
    short8 b3 = *(const short8*)(bB + 48 * 136 + ko);
    acc[0][0] = __builtin_amdgcn_mfma_f32_16x16x32_bf16(a0, b0, acc[0][0], 0, 0, 0);
    acc[0][1] = __builtin_amdgcn_mfma_f32_16x16x32_bf16(a0, b1, acc[0][1], 0, 0, 0);
    acc[0][2] = __builtin_amdgcn_mfma_f32_16x16x32_bf16(a0, b2, acc[0][2], 0, 0, 0);
    acc[0][3] = __builtin_amdgcn_mfma_f32_16x16x32_bf16(a0, b3, acc[0][3], 0, 0, 0);
    acc[1][0] = __builtin_amdgcn_mfma_f32_16x16x32_bf16(a1, b0, acc[1][0], 0, 0, 0);
    acc[1][1] = __builtin_amdgcn_mfma_f32_16x16x32_bf16(a1, b1, acc[1][1], 0, 0, 0);
    acc[1][2] = __builtin_amdgcn_mfma_f32_16x16x32_bf16(a1, b2, acc[1][2], 0, 0, 0);
    acc[1][3] = __builtin_amdgcn_mfma_f32_16x16x32_bf16(a1, b3, acc[1][3], 0, 0, 0);
  }

  // epilogue: D[row= w*32+rt*16+q*4+i][col= ft*16+m16] = acc[rt][ft][i]
  float wp = 0.f;
  #pragma unroll
  for (int rt = 0; rt < 2; ++rt) {
    #pragma unroll
    for (int i = 0; i < 4; ++i) {
      int row = w * 32 + rt * 16 + q * 4 + i;
      float inv_e = sInvE[row];
      int fr = sFam[row], frh = fr >> 4, frl = fr & 15;
      float es = 0.f, ps = 0.f;
      #pragma unroll
      for (int ft = 0; ft < 4; ++ft) {
        float sim = acc[rt][ft][i] * inv_e * pv[ft];
        es += __expf(4.f * sim - 4.f);       // arg in [-8,0]
        if (frl == m16 && frh == ft) ps = sim;
      }
      #pragma unroll
      for (int off = 1; off < 16; off <<= 1) {
        es += __shfl_xor(es, off);
        ps += __shfl_xor(ps, off);
      }
      if (m16 == 0) wp += 4.f + __logf(es) - 2.f * ps;
    }
  }
  wp += __shfl_xor(wp, 16);
  wp += __shfl_xor(wp, 32);
  if (lane == 0) sWp[w] = wp;
  __syncthreads();
  if (t == 0) bsums[blockIdx.x] = sWp[0] + sWp[1] + sWp[2] + sWp[3];
}

// ---------------- Pass D -----------------------------------------------------
__global__ __launch_bounds__(256) void pass_d(
    const float* __restrict__ bs, float* __restrict__ out, int nb, float invN)
{
  __shared__ float red[256];
  int t = threadIdx.x;
  float s = 0.f;
  for (int i = t; i < nb; i += 256) s += bs[i];
  red[t] = s;
  __syncthreads();
  for (int o = 128; o; o >>= 1) { if (t < o) red[t] += red[t + o]; __syncthreads(); }
  if (t == 0) out[0] = red[0] * invN;
}

extern "C" void kernel_launch(void* const* d_in, const int* in_sizes, int n_in,
                              void* d_out, int out_size, void* d_ws, size_t ws_size,
                              hipStream_t stream) {
  const float* emb = (const float*)d_in[0];
  const int* fam = (const int*)d_in[1];
  int N = in_sizes[0] / D_DIM;               // 262144
  int blocksA = N / 1024;                    // 256
  int blocksC = N / 128;                     // 2048

  // ws layout (float units):
  // psum[blocksA*8192] | pcnt[blocksA*64] | protoB(8192 ushort = 4096 f) |
  // pinv[64] | inv_en[N] | bsums[blocksC]
  float* ws = (float*)d_ws;
  float* psum = ws;
  size_t off = (size_t)blocksA * (F_NUM * D_DIM);
  int* pcnt = (int*)(ws + off);              off += (size_t)blocksA * F_NUM;
  unsigned short* protoB = (unsigned short*)(ws + off); off += (F_NUM * D_DIM) / 2;
  float* pinv = ws + off;                    off += F_NUM;
  float* inv_en = ws + off;                  off += (size_t)N;
  float* bsums = ws + off;

  pass_a<<<blocksA, 1024, 0, stream>>>(emb, fam, psum, pcnt, inv_en, N);
  pass_b<<<F_NUM, 256, 0, stream>>>(psum, pcnt, protoB, pinv);
  pass_c<<<blocksC, 256, 0, stream>>>(emb, fam, protoB, pinv, inv_en, bsums);
  pass_d<<<1, 256, 0, stream>>>(bsums, (float*)d_out, blocksC, 1.0f / (float)N);
}

// Round 3
// 291.850 us; speedup vs baseline: 1.4961x; 1.2342x over previous
//
#include <hip/hip_runtime.h>
#include <math.h>

// ProtoLoss: loss = mean_n( -2*sim[n,fam[n]] + logsumexp_f(4*sim[n,f]) )
// sim = (E.P_f)/(||e||*||p_f||), P = segment-mean of E by family.
// N=262144, D=128, F=64.
// A) segment sums+counts via WAVE-PRIVATE LDS accumulators (no atomics:
//    round-2 counters showed LDS atomicAdd costs ~217 cyc/instr)
// B) reduce 256 partials -> protos(bf16) + 1/||p||
// C) bf16 MFMA (128 rows x 64 fams, K=128) + fp32 row norms + fused lse
// D) final sum.

#define D_DIM 128
#define F_NUM 64

typedef __attribute__((ext_vector_type(8))) short short8;
typedef __attribute__((ext_vector_type(4))) float f32x4;

static __device__ __forceinline__ unsigned short f2bf(float x) {
  union { float f; unsigned u; } v; v.f = x;
  unsigned r = v.u + 0x7FFFu + ((v.u >> 16) & 1u);   // RNE
  return (unsigned short)(r >> 16);
}

// ---------------- Pass A -----------------------------------------------------
// grid 256 x 1024 thr (16 waves). Wave w: dim-slice s=w&3 (32 dims), replica
// rep=w>>2 (256 rows). Private acc region in LDS -> plain RMW, in-order DS
// pipe, no atomics. Rare same-family pair (f0==f1, wave-uniform branch)
// handled by cross-half shfl combine. Bank-free: addr%32 == lane%32.
__global__ __launch_bounds__(1024) void pass_a(
    const float* __restrict__ emb, const int* __restrict__ fam,
    float* __restrict__ psum, int* __restrict__ pcnt, int N)
{
  __shared__ float acc[16 * 64 * 32];     // 128 KB; wave w owns [w*2048,+2048)
  __shared__ int lcnt[4 * F_NUM];
  int t = threadIdx.x;
  float4* acc4 = (float4*)acc;
  #pragma unroll
  for (int k = 0; k < 8; ++k) acc4[t + k * 1024] = make_float4(0.f,0.f,0.f,0.f);
  if (t < 4 * F_NUM) lcnt[t] = 0;
  __syncthreads();

  int w = t >> 6, l = t & 63;
  int s = w & 3, rep = w >> 2;
  int h = l >> 5, d = l & 31;
  int col = s * 32 + d;
  float* my = &acc[w * 2048];             // [64 fams][32 dims]
  int B0 = blockIdx.x * 1024;
  int W0 = __builtin_amdgcn_readfirstlane(B0 + rep * 256);  // uniform -> s_load fams

  #pragma unroll 1
  for (int i = 0; i < 128; ++i) {
    int f0 = fam[W0 + 2 * i];             // uniform addr -> scalar load
    int f1 = fam[W0 + 2 * i + 1];
    int row = W0 + 2 * i + h;
    float v = emb[(size_t)row * D_DIM + col];   // 2 x 128B coalesced segments
    if (f0 == f1) {                        // wave-uniform, ~1/64 of iters
      float vo = __shfl_xor(v, 32);
      if (h == 0) {
        my[f0 * 32 + d] += v + vo;
        if (s == 0 && d == 0) lcnt[rep * F_NUM + f0] += 2;
      }
    } else {
      int f = h ? f1 : f0;
      my[f * 32 + d] += v;
      if (s == 0 && d == 0) lcnt[rep * F_NUM + f] += 1;
    }
  }
  __syncthreads();

  // merge 4 replicas -> block-private psum slot (streaming dwordx4 stores)
  float4* out4 = (float4*)(psum + (size_t)blockIdx.x * (F_NUM * D_DIM));
  #pragma unroll
  for (int k = 0; k < 2; ++k) {
    int idx4 = t + k * 1024;              // 0..2047 float4s
    int f = idx4 >> 5, c4 = idx4 & 31;
    int sl = c4 >> 3, dd = (c4 & 7) << 2;
    float4 r = make_float4(0.f,0.f,0.f,0.f);
    #pragma unroll
    for (int rp = 0; rp < 4; ++rp) {
      float4 a = *(const float4*)&acc[(rp * 4 + sl) * 2048 + f * 32 + dd];
      r.x += a.x; r.y += a.y; r.z += a.z; r.w += a.w;
    }
    out4[idx4] = r;
  }
  if (t < F_NUM)
    pcnt[blockIdx.x * F_NUM + t] =
        lcnt[t] + lcnt[F_NUM + t] + lcnt[2 * F_NUM + t] + lcnt[3 * F_NUM + t];
}

// ---------------- Pass B -----------------------------------------------------
// 64 blocks (one per family) x 256 thr: reduce 256 partials, counts, norm.
__global__ __launch_bounds__(256) void pass_b(
    const float* __restrict__ psum, const int* __restrict__ pcnt,
    unsigned short* __restrict__ protoB, float* __restrict__ pinv)
{
  __shared__ float red[256];
  __shared__ float scnt;
  int f = blockIdx.x, t = threadIdx.x;
  int d = t & 127, h = t >> 7;

  red[t] = (float)pcnt[t * F_NUM + f];
  __syncthreads();
  for (int o = 128; o; o >>= 1) { if (t < o) red[t] += red[t + o]; __syncthreads(); }
  if (t == 0) scnt = fmaxf(red[0], 1.0f);
  __syncthreads();

  float s = 0.f;
  #pragma unroll 4
  for (int i = 0; i < 128; ++i)
    s += psum[(size_t)(h + 2 * i) * (F_NUM * D_DIM) + f * D_DIM + d];
  red[t] = s;
  __syncthreads();
  float proto = 0.f;
  if (t < 128) proto = (red[t] + red[t + 128]) / scnt;
  __syncthreads();

  red[t] = (t < 128) ? proto * proto : 0.f;
  __syncthreads();
  for (int o = 128; o; o >>= 1) { if (t < o) red[t] += red[t + o]; __syncthreads(); }
  if (t == 0) pinv[f] = rsqrtf(fmaxf(red[0], 1e-24f));

  if (t < 128) protoB[f * D_DIM + t] = f2bf(proto);
}

// ---------------- Pass C -----------------------------------------------------
// 2048 blocks x 256 thr. Tile: 128 rows x 64 fams, K=128, bf16 MFMA 16x16x32.
// fp32 row norms computed during staging (exact, cross-lane reduce while the
// row's float4s are in registers). LDS padded 136 -> conflict-free b128.
__global__ __launch_bounds__(256) void pass_c(
    const float* __restrict__ emb, const int* __restrict__ fam,
    const unsigned short* __restrict__ protoB, const float* __restrict__ pinv,
    float* __restrict__ bsums)
{
  __shared__ __align__(16) unsigned short sA[128 * 136];   // 34816 B
  __shared__ __align__(16) unsigned short sB[F_NUM * 136]; // 17408 B
  __shared__ float sInvE[128];
  __shared__ int   sFam[128];
  __shared__ float sWp[4];

  int t = threadIdx.x;
  int R0 = blockIdx.x * 128;
  const float4* src = (const float4*)emb;

  // stage A: fp32 -> bf16 -> LDS; 32 consecutive lanes hold one row -> exact
  // fp32 norm via 5 shfl_xor while data is in registers.
  #pragma unroll
  for (int it = 0; it < 16; ++it) {
    int idx = it * 256 + t;                 // 0..4095 float4s
    int row = idx >> 5, c4 = idx & 31;
    float4 v = src[(size_t)(R0 + row) * 32 + c4];
    float nq = v.x * v.x + v.y * v.y + v.z * v.z + v.w * v.w;
    nq += __shfl_xor(nq, 1);  nq += __shfl_xor(nq, 2);  nq += __shfl_xor(nq, 4);
    nq += __shfl_xor(nq, 8);  nq += __shfl_xor(nq, 16);
    if ((t & 31) == 0) sInvE[row] = rsqrtf(nq);
    ushort4 u;
    u.x = f2bf(v.x); u.y = f2bf(v.y); u.z = f2bf(v.z); u.w = f2bf(v.w);
    *(ushort4*)&sA[row * 136 + (c4 << 2)] = u;
  }
  const ushort4* pb = (const ushort4*)protoB;
  #pragma unroll
  for (int it = 0; it < 8; ++it) {
    int idx = it * 256 + t;                 // 0..2047 ushort4s
    int f = idx >> 5, c4 = idx & 31;
    *(ushort4*)&sB[f * 136 + (c4 << 2)] = pb[idx];
  }
  if (t < 128) sFam[t] = fam[R0 + t];
  __syncthreads();

  int w = t >> 6, lane = t & 63, m16 = lane & 15, q = lane >> 4;
  float pv[4];
  #pragma unroll
  for (int ft = 0; ft < 4; ++ft) pv[ft] = pinv[ft * 16 + m16];

  f32x4 acc[2][4] = {};
  const unsigned short* aB0 = &sA[(w * 32 + m16) * 136 + q * 8];
  const unsigned short* aB1 = aB0 + 16 * 136;
  const unsigned short* bB  = &sB[m16 * 136 + q * 8];

  #pragma unroll
  for (int ks = 0; ks < 4; ++ks) {
    int ko = ks * 32;
    short8 a0 = *(const short8*)(aB0 + ko);
    short8 a1 = *(const short8*)(aB1 + ko);
    short8 b0 = *(const short8*)(bB + ko);
    short8 b1 = *(const short8*)(bB + 16 * 136 + ko);
    short8 b2 = *(const short8*)(bB + 32 * 136 + ko);
    short8 b3 = *(const short8*)(bB + 48 * 136 + ko);
    acc[0][0] = __builtin_amdgcn_mfma_f32_16x16x32_bf16(a0, b0, acc[0][0], 0, 0, 0);
    acc[0][1] = __builtin_amdgcn_mfma_f32_16x16x32_bf16(a0, b1, acc[0][1], 0, 0, 0);
    acc[0][2] = __builtin_amdgcn_mfma_f32_16x16x32_bf16(a0, b2, acc[0][2], 0, 0, 0);
    acc[0][3] = __builtin_amdgcn_mfma_f32_16x16x32_bf16(a0, b3, acc[0][3], 0, 0, 0);
    acc[1][0] = __builtin_amdgcn_mfma_f32_16x16x32_bf16(a1, b0, acc[1][0], 0, 0, 0);
    acc[1][1] = __builtin_amdgcn_mfma_f32_16x16x32_bf16(a1, b1, acc[1][1], 0, 0, 0);
    acc[1][2] = __builtin_amdgcn_mfma_f32_16x16x32_bf16(a1, b2, acc[1][2], 0, 0, 0);
    acc[1][3] = __builtin_amdgcn_mfma_f32_16x16x32_bf16(a1, b3, acc[1][3], 0, 0, 0);
  }

  // epilogue: D[row= w*32+rt*16+q*4+i][col= ft*16+m16] = acc[rt][ft][i]
  float wp = 0.f;
  #pragma unroll
  for (int rt = 0; rt < 2; ++rt) {
    #pragma unroll
    for (int i = 0; i < 4; ++i) {
      int row = w * 32 + rt * 16 + q * 4 + i;
      float inv_e = sInvE[row];
      int fr = sFam[row], frh = fr >> 4, frl = fr & 15;
      float es = 0.f, ps = 0.f;
      #pragma unroll
      for (int ft = 0; ft < 4; ++ft) {
        float sim = acc[rt][ft][i] * inv_e * pv[ft];
        es += __expf(4.f * sim - 4.f);       // arg in [-8,0]
        if (frl == m16 && frh == ft) ps = sim;
      }
      #pragma unroll
      for (int off = 1; off < 16; off <<= 1) {
        es += __shfl_xor(es, off);
        ps += __shfl_xor(ps, off);
      }
      if (m16 == 0) wp += 4.f + __logf(es) - 2.f * ps;
    }
  }
  wp += __shfl_xor(wp, 16);
  wp += __shfl_xor(wp, 32);
  if (lane == 0) sWp[w] = wp;
  __syncthreads();
  if (t == 0) bsums[blockIdx.x] = sWp[0] + sWp[1] + sWp[2] + sWp[3];
}

// ---------------- Pass D -----------------------------------------------------
__global__ __launch_bounds__(256) void pass_d(
    const float* __restrict__ bs, float* __restrict__ out, int nb, float invN)
{
  __shared__ float red[256];
  int t = threadIdx.x;
  float s = 0.f;
  for (int i = t; i < nb; i += 256) s += bs[i];
  red[t] = s;
  __syncthreads();
  for (int o = 128; o; o >>= 1) { if (t < o) red[t] += red[t + o]; __syncthreads(); }
  if (t == 0) out[0] = red[0] * invN;
}

extern "C" void kernel_launch(void* const* d_in, const int* in_sizes, int n_in,
                              void* d_out, int out_size, void* d_ws, size_t ws_size,
                              hipStream_t stream) {
  const float* emb = (const float*)d_in[0];
  const int* fam = (const int*)d_in[1];
  int N = in_sizes[0] / D_DIM;               // 262144
  int blocksA = N / 1024;                    // 256
  int blocksC = N / 128;                     // 2048

  // ws (float units): psum[256*8192] | pcnt[256*64] | protoB(8192 us = 4096 f)
  // | pinv[64] | bsums[2048]
  float* ws = (float*)d_ws;
  float* psum = ws;
  size_t off = (size_t)blocksA * (F_NUM * D_DIM);
  int* pcnt = (int*)(ws + off);              off += (size_t)blocksA * F_NUM;
  unsigned short* protoB = (unsigned short*)(ws + off); off += (F_NUM * D_DIM) / 2;
  float* pinv = ws + off;                    off += F_NUM;
  float* bsums = ws + off;

  pass_a<<<blocksA, 1024, 0, stream>>>(emb, fam, psum, pcnt, N);
  pass_b<<<F_NUM, 256, 0, stream>>>(psum, pcnt, protoB, pinv);
  pass_c<<<blocksC, 256, 0, stream>>>(emb, fam, protoB, pinv, bsums);
  pass_d<<<1, 256, 0, stream>>>(bsums, (float*)d_out, blocksC, 1.0f / (float)N);
}

// Round 4
// 252.104 us; speedup vs baseline: 1.7320x; 1.1577x over previous
//
#include <hip/hip_runtime.h>
#include <math.h>

// ProtoLoss: loss = mean_n( -2*sim[n,fam[n]] + logsumexp_f(4*sim[n,f]) )
// sim = (E.P_f)/(||e||*||p_f||), P = segment-mean of E by family.
// N=262144, D=128, F=64.
// A) segment sums+counts, wave-private LDS accumulators, 16-deep load batching
//    (round-3 counters: 1 load in flight -> latency-bound at 2 B/cyc/CU)
// B) reduce 256 partials -> protos(bf16) + 1/||p|| (1024 thr, 8-way split)
// C) bf16 MFMA (128 rows x 64 fams, K=128) + fp32 row norms + fused lse,
//    finished with one global atomic per block (pass_d folded in).

#define D_DIM 128
#define F_NUM 64

typedef __attribute__((ext_vector_type(8))) short short8;
typedef __attribute__((ext_vector_type(4))) float f32x4;

static __device__ __forceinline__ unsigned short f2bf(float x) {
  union { float f; unsigned u; } v; v.f = x;
  unsigned r = v.u + 0x7FFFu + ((v.u >> 16) & 1u);   // RNE
  return (unsigned short)(r >> 16);
}

// ---------------- Pass A -----------------------------------------------------
// grid 256 x 512 thr (8 waves). Wave w: slice s=w&1 (64 dims), replica
// rep=w>>1 (256 rows). One row per wave-instr: lane l = dim s*64+l -> no
// same-family collision, no branches. 16 loads batched -> 4 KB in flight/wave.
// RMW addrs are 64 consecutive words (2-way bank alias = free).
__global__ __launch_bounds__(512) void pass_a(
    const float* __restrict__ emb, const int* __restrict__ fam,
    float* __restrict__ psum, int* __restrict__ pcnt)
{
  __shared__ float acc[8 * 4096];         // 128 KB; wave w owns [w*4096,+4096)
  __shared__ int lcnt[4 * F_NUM];
  int t = threadIdx.x;
  float4 z = make_float4(0.f, 0.f, 0.f, 0.f);
  float4* a4 = (float4*)acc;
  #pragma unroll
  for (int k = 0; k < 16; ++k) a4[t + k * 512] = z;
  if (t < 4 * F_NUM) lcnt[t] = 0;
  __syncthreads();

  int w = t >> 6, l = t & 63;
  int s = w & 1, rep = w >> 1;
  float* my = acc + w * 4096;             // [64 fams][64 dims]
  int base = __builtin_amdgcn_readfirstlane(blockIdx.x * 1024 + rep * 256);
  const float* ecol = emb + (size_t)base * D_DIM + s * 64 + l;

  #pragma unroll 1
  for (int b = 0; b < 16; ++b) {
    float v[16]; int f[16];
    #pragma unroll
    for (int j = 0; j < 16; ++j) {        // 16 independent 256B loads in flight
      int r = b * 16 + j;
      v[j] = ecol[(size_t)r * D_DIM];
      f[j] = fam[base + r];               // wave-uniform -> scalar loads
    }
    #pragma unroll
    for (int j = 0; j < 16; ++j)
      my[f[j] * 64 + l] += v[j];          // in-order DS pipe, private region
    if (s == 0 && l == 0) {
      #pragma unroll
      for (int j = 0; j < 16; ++j) lcnt[rep * F_NUM + f[j]] += 1;
    }
  }
  __syncthreads();

  // merge 4 replicas -> block-private psum slot (streaming dwordx4 stores)
  float4* out4 = (float4*)(psum + (size_t)blockIdx.x * (F_NUM * D_DIM));
  #pragma unroll
  for (int k = 0; k < 4; ++k) {
    int idx4 = t + k * 512;               // 0..2047 float4s of [f][128]
    int f = idx4 >> 5, c4 = idx4 & 31;
    int ss = c4 >> 4, ll4 = (c4 & 15) << 2;
    float4 r = z;
    #pragma unroll
    for (int rp = 0; rp < 4; ++rp) {
      float4 a = *(const float4*)&acc[(rp * 2 + ss) * 4096 + f * 64 + ll4];
      r.x += a.x; r.y += a.y; r.z += a.z; r.w += a.w;
    }
    out4[idx4] = r;
  }
  if (t < F_NUM)
    pcnt[blockIdx.x * F_NUM + t] =
        lcnt[t] + lcnt[F_NUM + t] + lcnt[2 * F_NUM + t] + lcnt[3 * F_NUM + t];
}

// ---------------- Pass B -----------------------------------------------------
// 64 blocks (one per family) x 1024 thr: 8-way partial split, unroll 8.
__global__ __launch_bounds__(1024) void pass_b(
    const float* __restrict__ psum, const int* __restrict__ pcnt,
    unsigned short* __restrict__ protoB, float* __restrict__ pinv)
{
  __shared__ float red[1024];
  __shared__ float rc[256];
  __shared__ float prot[128];
  __shared__ float scnt;
  int f = blockIdx.x, t = threadIdx.x;
  int d = t & 127, h = t >> 7;            // h in 0..7

  if (t < 256) rc[t] = (float)pcnt[t * F_NUM + f];
  float s = 0.f;
  #pragma unroll 8
  for (int i = 0; i < 32; ++i)
    s += psum[(size_t)(h + 8 * i) * (F_NUM * D_DIM) + f * D_DIM + d];
  red[t] = s;
  __syncthreads();
  if (t < 128) {
    float p = 0.f;
    #pragma unroll
    for (int hh = 0; hh < 8; ++hh) p += red[hh * 128 + d];
    prot[d] = p;                          // raw sum; scaled after count known
  }
  if (t < 64) rc[t] += rc[t + 64] + rc[t + 128] + rc[t + 192];
  __syncthreads();
  if (t < 16) rc[t] += rc[t + 16] + rc[t + 32] + rc[t + 48];
  __syncthreads();
  if (t < 4) rc[t] += rc[t + 4] + rc[t + 8] + rc[t + 12];
  __syncthreads();
  if (t == 0) scnt = fmaxf(rc[0] + rc[1] + rc[2] + rc[3], 1.0f);
  __syncthreads();
  float proto = 0.f;
  if (t < 128) {
    proto = prot[d] / scnt;
    red[d] = proto * proto;
  }
  __syncthreads();
  if (t < 32) red[t] += red[t + 32] + red[t + 64] + red[t + 96];
  __syncthreads();
  if (t < 8) red[t] += red[t + 8] + red[t + 16] + red[t + 24];
  __syncthreads();
  if (t < 2) red[t] += red[t + 2] + red[t + 4] + red[t + 6];
  __syncthreads();
  if (t == 0) pinv[f] = rsqrtf(fmaxf(red[0] + red[1], 1e-24f));
  if (t < 128) protoB[f * D_DIM + t] = f2bf(proto);
}

// ---------------- Pass C -----------------------------------------------------
// 2048 blocks x 256 thr. Tile: 128 rows x 64 fams, K=128, bf16 MFMA 16x16x32.
// fp32 row norms during staging (shfl-reduce in-register). Pad 136 -> b128
// conflict-free. Finish: one unsafeAtomicAdd per block into d_out.
__global__ __launch_bounds__(256) void pass_c(
    const float* __restrict__ emb, const int* __restrict__ fam,
    const unsigned short* __restrict__ protoB, const float* __restrict__ pinv,
    float* __restrict__ out, float invN)
{
  __shared__ __align__(16) unsigned short sA[128 * 136];   // 34816 B
  __shared__ __align__(16) unsigned short sB[F_NUM * 136]; // 17408 B
  __shared__ float sInvE[128];
  __shared__ int   sFam[128];
  __shared__ float sWp[4];

  int t = threadIdx.x;
  int R0 = blockIdx.x * 128;
  const float4* src = (const float4*)emb;

  #pragma unroll
  for (int it = 0; it < 16; ++it) {
    int idx = it * 256 + t;                 // 0..4095 float4s
    int row = idx >> 5, c4 = idx & 31;
    float4 v = src[(size_t)(R0 + row) * 32 + c4];
    float nq = v.x * v.x + v.y * v.y + v.z * v.z + v.w * v.w;
    nq += __shfl_xor(nq, 1);  nq += __shfl_xor(nq, 2);  nq += __shfl_xor(nq, 4);
    nq += __shfl_xor(nq, 8);  nq += __shfl_xor(nq, 16);
    if ((t & 31) == 0) sInvE[row] = rsqrtf(nq);
    ushort4 u;
    u.x = f2bf(v.x); u.y = f2bf(v.y); u.z = f2bf(v.z); u.w = f2bf(v.w);
    *(ushort4*)&sA[row * 136 + (c4 << 2)] = u;
  }
  const ushort4* pb = (const ushort4*)protoB;
  #pragma unroll
  for (int it = 0; it < 8; ++it) {
    int idx = it * 256 + t;                 // 0..2047 ushort4s
    int f = idx >> 5, c4 = idx & 31;
    *(ushort4*)&sB[f * 136 + (c4 << 2)] = pb[idx];
  }
  if (t < 128) sFam[t] = fam[R0 + t];
  __syncthreads();

  int w = t >> 6, lane = t & 63, m16 = lane & 15, q = lane >> 4;
  float pv[4];
  #pragma unroll
  for (int ft = 0; ft < 4; ++ft) pv[ft] = pinv[ft * 16 + m16];

  f32x4 acc[2][4] = {};
  const unsigned short* aB0 = &sA[(w * 32 + m16) * 136 + q * 8];
  const unsigned short* aB1 = aB0 + 16 * 136;
  const unsigned short* bB  = &sB[m16 * 136 + q * 8];

  #pragma unroll
  for (int ks = 0; ks < 4; ++ks) {
    int ko = ks * 32;
    short8 a0 = *(const short8*)(aB0 + ko);
    short8 a1 = *(const short8*)(aB1 + ko);
    short8 b0 = *(const short8*)(bB + ko);
    short8 b1 = *(const short8*)(bB + 16 * 136 + ko);
    short8 b2 = *(const short8*)(bB + 32 * 136 + ko);
    short8 b3 = *(const short8*)(bB + 48 * 136 + ko);
    acc[0][0] = __builtin_amdgcn_mfma_f32_16x16x32_bf16(a0, b0, acc[0][0], 0, 0, 0);
    acc[0][1] = __builtin_amdgcn_mfma_f32_16x16x32_bf16(a0, b1, acc[0][1], 0, 0, 0);
    acc[0][2] = __builtin_amdgcn_mfma_f32_16x16x32_bf16(a0, b2, acc[0][2], 0, 0, 0);
    acc[0][3] = __builtin_amdgcn_mfma_f32_16x16x32_bf16(a0, b3, acc[0][3], 0, 0, 0);
    acc[1][0] = __builtin_amdgcn_mfma_f32_16x16x32_bf16(a1, b0, acc[1][0], 0, 0, 0);
    acc[1][1] = __builtin_amdgcn_mfma_f32_16x16x32_bf16(a1, b1, acc[1][1], 0, 0, 0);
    acc[1][2] = __builtin_amdgcn_mfma_f32_16x16x32_bf16(a1, b2, acc[1][2], 0, 0, 0);
    acc[1][3] = __builtin_amdgcn_mfma_f32_16x16x32_bf16(a1, b3, acc[1][3], 0, 0, 0);
  }

  // epilogue: D[row= w*32+rt*16+q*4+i][col= ft*16+m16] = acc[rt][ft][i]
  float wp = 0.f;
  #pragma unroll
  for (int rt = 0; rt < 2; ++rt) {
    #pragma unroll
    for (int i = 0; i < 4; ++i) {
      int row = w * 32 + rt * 16 + q * 4 + i;
      float inv_e = sInvE[row];
      int fr = sFam[row], frh = fr >> 4, frl = fr & 15;
      float es = 0.f, ps = 0.f;
      #pragma unroll
      for (int ft = 0; ft < 4; ++ft) {
        float sim = acc[rt][ft][i] * inv_e * pv[ft];
        es += __expf(4.f * sim - 4.f);       // arg in [-8,0]
        if (frl == m16 && frh == ft) ps = sim;
      }
      #pragma unroll
      for (int off = 1; off < 16; off <<= 1) {
        es += __shfl_xor(es, off);
        ps += __shfl_xor(ps, off);
      }
      if (m16 == 0) wp += 4.f + __logf(es) - 2.f * ps;
    }
  }
  wp += __shfl_xor(wp, 16);
  wp += __shfl_xor(wp, 32);
  if (lane == 0) sWp[w] = wp;
  __syncthreads();
  if (t == 0)
    unsafeAtomicAdd(out, (sWp[0] + sWp[1] + sWp[2] + sWp[3]) * invN);
}

extern "C" void kernel_launch(void* const* d_in, const int* in_sizes, int n_in,
                              void* d_out, int out_size, void* d_ws, size_t ws_size,
                              hipStream_t stream) {
  const float* emb = (const float*)d_in[0];
  const int* fam = (const int*)d_in[1];
  int N = in_sizes[0] / D_DIM;               // 262144
  int blocksA = N / 1024;                    // 256
  int blocksC = N / 128;                     // 2048

  // ws (float units): psum[256*8192] | pcnt[256*64] | protoB(8192 us) | pinv[64]
  float* ws = (float*)d_ws;
  float* psum = ws;
  size_t off = (size_t)blocksA * (F_NUM * D_DIM);
  int* pcnt = (int*)(ws + off);              off += (size_t)blocksA * F_NUM;
  unsigned short* protoB = (unsigned short*)(ws + off); off += (F_NUM * D_DIM) / 2;
  float* pinv = ws + off;

  hipMemsetAsync(d_out, 0, sizeof(float), stream);
  pass_a<<<blocksA, 512, 0, stream>>>(emb, fam, psum, pcnt);
  pass_b<<<F_NUM, 1024, 0, stream>>>(psum, pcnt, protoB, pinv);
  pass_c<<<blocksC, 256, 0, stream>>>(emb, fam, protoB, pinv,
                                      (float*)d_out, 1.0f / (float)N);
}

// Round 6
// 248.210 us; speedup vs baseline: 1.7591x; 1.0157x over previous
//
#include <hip/hip_runtime.h>
#include <math.h>

// ProtoLoss: loss = mean_n( -2*sim[n,fam[n]] + logsumexp_f(4*sim[n,f]) )
// sim = (e.p)/(||e||*||p||)  -- scale-invariant in p, so the segment-mean's
// count division cancels: p_hat = raw_sum/||raw_sum||. No counts anywhere.
// N=262144, D=128, F=64.
// A) segment raw sums (wave-private LDS acc, 16-deep batched loads) + write
//    e_hat = e/||e|| as packed bf16 (67 MB -> L3) for pass_c.
// B1) 256-block reduce of 256 partials -> protoRaw fp32
// B2) 1-block normalize -> protoB bf16
// C) bf16 MFMA (128 rows x 64 fams, K=128) on normalized operands + fused
//    lse epilogue; one unsafeAtomicAdd per block into d_out.

#define D_DIM 128
#define F_NUM 64

typedef __attribute__((ext_vector_type(8))) short short8;
typedef __attribute__((ext_vector_type(4))) float f32x4;

static __device__ __forceinline__ unsigned short f2bf(float x) {
  union { float f; unsigned u; } v; v.f = x;
  unsigned r = v.u + 0x7FFFu + ((v.u >> 16) & 1u);   // RNE
  return (unsigned short)(r >> 16);
}

// ---------------- Pass A -----------------------------------------------------
// grid N/1024 x 256 thr (4 waves). Wave = replica: private [64][128] acc
// (4 x 32 KB = 128 KB LDS). One row per wave-instr: lane l holds dims
// 2l,2l+1 (float2). Full-wave shfl reduce -> exact fp32 norm -> e_hat bf16.
// 16 loads batched -> 8 KB in flight/wave covers HBM latency.
__global__ __launch_bounds__(256) void pass_a(
    const float* __restrict__ emb, const int* __restrict__ fam,
    float* __restrict__ psum, unsigned int* __restrict__ ehat)
{
  __shared__ float acc[4 * F_NUM * D_DIM];   // 128 KB; wave w owns [w*8192,+8192)
  int t = threadIdx.x;
  float4 z = make_float4(0.f, 0.f, 0.f, 0.f);
  float4* a4 = (float4*)acc;
  #pragma unroll
  for (int k = 0; k < 32; ++k) a4[t + k * 256] = z;
  __syncthreads();

  int w = t >> 6, l = t & 63;
  float* my = acc + w * 8192;                // [64 fams][128 dims]
  int base = __builtin_amdgcn_readfirstlane(blockIdx.x * 1024 + w * 256);
  const float2* e2 = (const float2*)emb;

  #pragma unroll 1
  for (int b = 0; b < 16; ++b) {
    float2 v[16]; int f[16];
    #pragma unroll
    for (int j = 0; j < 16; ++j) {           // 16 independent 512B row loads
      int r = base + b * 16 + j;
      v[j] = e2[(size_t)r * 64 + l];
      f[j] = fam[r];                         // uniform -> s_load_dwordx8
    }
    #pragma unroll
    for (int j = 0; j < 16; ++j) {
      float x = v[j].x, y = v[j].y;
      float nq = x * x + y * y;
      nq += __shfl_xor(nq, 1);  nq += __shfl_xor(nq, 2);  nq += __shfl_xor(nq, 4);
      nq += __shfl_xor(nq, 8);  nq += __shfl_xor(nq, 16); nq += __shfl_xor(nq, 32);
      float inv = rsqrtf(fmaxf(nq, 1e-20f));
      ehat[(size_t)(base + b * 16 + j) * 64 + l] =
          ((unsigned)f2bf(y * inv) << 16) | f2bf(x * inv);
      float2* dst = (float2*)&my[f[j] * D_DIM + 2 * l];
      float2 cur = *dst;                     // wave-private, in-order DS pipe
      cur.x += x; cur.y += y;
      *dst = cur;
    }
  }
  __syncthreads();

  // merge 4 replicas -> block-private psum slot (streaming dwordx4 stores)
  float4* out4 = (float4*)(psum + (size_t)blockIdx.x * (F_NUM * D_DIM));
  #pragma unroll
  for (int k = 0; k < 8; ++k) {
    int idx4 = t + k * 256;                  // 0..2047 float4s of [f][128]
    float4 r = z;
    #pragma unroll
    for (int rp = 0; rp < 4; ++rp) {
      float4 a = a4[rp * 2048 + idx4];
      r.x += a.x; r.y += a.y; r.z += a.z; r.w += a.w;
    }
    out4[idx4] = r;
  }
}

// ---------------- Pass B1 ----------------------------------------------------
// 256 blocks (f x dim-quarter) x 256 thr: reduce nPart partials -> protoRaw.
__global__ __launch_bounds__(256) void pass_b1(
    const float* __restrict__ psum, float* __restrict__ protoRaw, int nPart)
{
  __shared__ float red[256];
  int f = blockIdx.x >> 2, qd = blockIdx.x & 3;
  int t = threadIdx.x;
  int d = qd * 32 + (t & 31), p0 = t >> 5;   // 8 partial-groups
  int per = nPart >> 3;
  float s = 0.f;
  #pragma unroll 8
  for (int i = 0; i < per; ++i)
    s += psum[(size_t)(p0 + 8 * i) * (F_NUM * D_DIM) + f * D_DIM + d];
  red[t] = s;
  __syncthreads();
  if (t < 32) {
    float r = 0.f;
    #pragma unroll
    for (int k = 0; k < 8; ++k) r += red[k * 32 + t];
    protoRaw[f * D_DIM + qd * 32 + t] = r;
  }
}

// ---------------- Pass B2 ----------------------------------------------------
// 1 block x 256 thr: thread (f=t>>2, quarter pt=t&3) -> normalize, bf16.
__global__ __launch_bounds__(256) void pass_b2(
    const float* __restrict__ protoRaw, unsigned short* __restrict__ protoB)
{
  int t = threadIdx.x, f = t >> 2, pt = t & 3;
  const float4* src = (const float4*)(protoRaw + f * D_DIM + pt * 32);
  float4 v[8];
  float n2 = 0.f;
  #pragma unroll
  for (int i = 0; i < 8; ++i) {
    v[i] = src[i];
    n2 += v[i].x * v[i].x + v[i].y * v[i].y + v[i].z * v[i].z + v[i].w * v[i].w;
  }
  n2 += __shfl_xor(n2, 1);                   // quad = same f
  n2 += __shfl_xor(n2, 2);
  float inv = rsqrtf(fmaxf(n2, 1e-24f));     // zero-family -> p_hat=0 -> sim=0
  ushort4* dst = (ushort4*)(protoB + f * D_DIM + pt * 32);
  #pragma unroll
  for (int i = 0; i < 8; ++i) {
    ushort4 u;
    u.x = f2bf(v[i].x * inv); u.y = f2bf(v[i].y * inv);
    u.z = f2bf(v[i].z * inv); u.w = f2bf(v[i].w * inv);
    dst[i] = u;
  }
}

// ---------------- Pass C -----------------------------------------------------
// N/128 blocks x 256 thr. Tile: 128 rows x 64 fams, K=128, bf16 MFMA 16x16x32.
// Operands pre-normalized -> sim = MFMA acc directly. LDS 52 KB -> 3 blk/CU.
__global__ __launch_bounds__(256) void pass_c(
    const unsigned short* __restrict__ ehat, const int* __restrict__ fam,
    const unsigned short* __restrict__ protoB,
    float* __restrict__ out, float invN)
{
  __shared__ __align__(16) unsigned short sA[128 * 136];   // 34816 B
  __shared__ __align__(16) unsigned short sB[F_NUM * 136]; // 17408 B
  __shared__ int   sFam[128];
  __shared__ float sWp[4];

  int t = threadIdx.x;
  int R0 = blockIdx.x * 128;
  const short8* srcA = (const short8*)ehat;
  const short8* srcB = (const short8*)protoB;

  #pragma unroll
  for (int it = 0; it < 8; ++it) {
    int idx = it * 256 + t;                  // 0..2047 16B-chunks
    int row = idx >> 4, c8 = idx & 15;       // 4 rows/wave = 1KB contiguous
    *(short8*)&sA[row * 136 + c8 * 8] = srcA[(size_t)(R0 + row) * 16 + c8];
  }
  #pragma unroll
  for (int it = 0; it < 4; ++it) {
    int idx = it * 256 + t;                  // 0..1023
    int row = idx >> 4, c8 = idx & 15;
    *(short8*)&sB[row * 136 + c8 * 8] = srcB[idx];
  }
  if (t < 128) sFam[t] = fam[R0 + t];
  __syncthreads();

  int w = t >> 6, lane = t & 63, m16 = lane & 15, q = lane >> 4;

  f32x4 acc[2][4] = {};
  const unsigned short* aB0 = &sA[(w * 32 + m16) * 136 + q * 8];
  const unsigned short* aB1 = aB0 + 16 * 136;
  const unsigned short* bB  = &sB[m16 * 136 + q * 8];

  #pragma unroll
  for (int ks = 0; ks < 4; ++ks) {
    int ko = ks * 32;
    short8 a0 = *(const short8*)(aB0 + ko);
    short8 a1 = *(const short8*)(aB1 + ko);
    short8 b0 = *(const short8*)(bB + ko);
    short8 b1 = *(const short8*)(bB + 16 * 136 + ko);
    short8 b2 = *(const short8*)(bB + 32 * 136 + ko);
    short8 b3 = *(const short8*)(bB + 48 * 136 + ko);
    acc[0][0] = __builtin_amdgcn_mfma_f32_16x16x32_bf16(a0, b0, acc[0][0], 0, 0, 0);
    acc[0][1] = __builtin_amdgcn_mfma_f32_16x16x32_bf16(a0, b1, acc[0][1], 0, 0, 0);
    acc[0][2] = __builtin_amdgcn_mfma_f32_16x16x32_bf16(a0, b2, acc[0][2], 0, 0, 0);
    acc[0][3] = __builtin_amdgcn_mfma_f32_16x16x32_bf16(a0, b3, acc[0][3], 0, 0, 0);
    acc[1][0] = __builtin_amdgcn_mfma_f32_16x16x32_bf16(a1, b0, acc[1][0], 0, 0, 0);
    acc[1][1] = __builtin_amdgcn_mfma_f32_16x16x32_bf16(a1, b1, acc[1][1], 0, 0, 0);
    acc[1][2] = __builtin_amdgcn_mfma_f32_16x16x32_bf16(a1, b2, acc[1][2], 0, 0, 0);
    acc[1][3] = __builtin_amdgcn_mfma_f32_16x16x32_bf16(a1, b3, acc[1][3], 0, 0, 0);
  }

  // epilogue: sim = acc (normalized operands).
  // D[row= w*32+rt*16+q*4+i][col= ft*16+m16] = acc[rt][ft][i]
  float wp = 0.f;
  #pragma unroll
  for (int rt = 0; rt < 2; ++rt) {
    #pragma unroll
    for (int i = 0; i < 4; ++i) {
      int row = w * 32 + rt * 16 + q * 4 + i;
      int fr = sFam[row], frh = fr >> 4, frl = fr & 15;
      float es = 0.f, ps = 0.f;
      #pragma unroll
      for (int ft = 0; ft < 4; ++ft) {
        float sim = acc[rt][ft][i];
        es += __expf(4.f * sim - 4.f);       // sim in [-1,1] -> arg in [-8,0]
        if (frl == m16 && frh == ft) ps = sim;
      }
      #pragma unroll
      for (int off = 1; off < 16; off <<= 1) {
        es += __shfl_xor(es, off);
        ps += __shfl_xor(ps, off);
      }
      if (m16 == 0) wp += 4.f + __logf(es) - 2.f * ps;
    }
  }
  wp += __shfl_xor(wp, 16);
  wp += __shfl_xor(wp, 32);
  if (lane == 0) sWp[w] = wp;
  __syncthreads();
  if (t == 0)
    unsafeAtomicAdd(out, (sWp[0] + sWp[1] + sWp[2] + sWp[3]) * invN);
}

extern "C" void kernel_launch(void* const* d_in, const int* in_sizes, int n_in,
                              void* d_out, int out_size, void* d_ws, size_t ws_size,
                              hipStream_t stream) {
  const float* emb = (const float*)d_in[0];
  const int* fam = (const int*)d_in[1];
  int N = in_sizes[0] / D_DIM;               // 262144
  int blocksA = N / 1024;                    // 256
  int blocksC = N / 128;                     // 2048

  // ws (float units): psum[256*8192] | protoRaw[8192] | protoB(8192 ushort)
  // | ehat[N*64 uint]
  float* ws = (float*)d_ws;
  float* psum = ws;
  size_t off = (size_t)blocksA * (F_NUM * D_DIM);
  float* protoRaw = ws + off;                off += F_NUM * D_DIM;
  unsigned short* protoB = (unsigned short*)(ws + off); off += (F_NUM * D_DIM) / 2;
  unsigned int* ehat = (unsigned int*)(ws + off);

  (void)hipMemsetAsync(d_out, 0, sizeof(float), stream);
  pass_a<<<blocksA, 256, 0, stream>>>(emb, fam, psum, ehat);
  pass_b1<<<4 * F_NUM, 256, 0, stream>>>(psum, protoRaw, blocksA);
  pass_b2<<<1, 256, 0, stream>>>(protoRaw, protoB);
  pass_c<<<blocksC, 256, 0, stream>>>((const unsigned short*)ehat, fam, protoB,
                                      (float*)d_out, 1.0f / (float)N);
}